// Round 3
// baseline (18704.468 us; speedup 1.0000x reference)
//
#include <hip/hip_runtime.h>
#include <hip/hip_bf16.h>

#define BB 256
#define TT 2000
#define FF 42
#define HVAD 24
#define HNOI 48
#define HDEN 96
#define NTHREADS 320

__device__ __forceinline__ float bf2f(__hip_bfloat16 v) { return __bfloat162float(v); }
__device__ __forceinline__ float sig(float x) { return 1.0f / (1.0f + __expf(-x)); }
__device__ __forceinline__ float unpk_lo(unsigned u) {
    union { unsigned u; float f; } c; c.u = u << 16; return c.f;
}
__device__ __forceinline__ float unpk_hi(unsigned u) {
    union { unsigned u; float f; } c; c.u = u & 0xffff0000u; return c.f;
}
// fp32 -> bf16 bits, round-to-nearest-even (no __hip_bfloat16 internals)
__device__ __forceinline__ unsigned f2bfbits(float f) {
    union { float f; unsigned u; } c; c.f = f;
    unsigned r = c.u + 0x7FFFu + ((c.u >> 16) & 1u);
    return r >> 16;
}
__device__ __forceinline__ unsigned pack2(float a, float b) {
    return f2bfbits(a) | (f2bfbits(b) << 16);
}
__device__ __forceinline__ float gload(const void* p, int i, bool f32) {
    return f32 ? ((const float*)p)[i] : bf2f(((const __hip_bfloat16*)p)[i]);
}

// W[O][K] row-major, K even -> packed bf16 pairs transposed:
// dst[kp*O + o] holds (W[o][2kp], W[o][2kp+1]).  Kw = K/2.
__device__ __forceinline__ void load_Tp(unsigned* dst, const void* src,
                                        int O, int Kw, int tid, int nt, bool f32) {
    for (int i = tid; i < O * Kw; i += nt) {
        int o = i / Kw, kp = i % Kw;
        unsigned w;
        if (f32) {
            const float* s = (const float*)src;
            w = pack2(s[2 * i], s[2 * i + 1]);
        } else {
            w = ((const unsigned*)src)[i];
        }
        dst[kp * O + o] = w;
    }
}
// W[O][K] row-major -> fp32 transposed dst[k*O + o]
__device__ __forceinline__ void load_T(float* dst, const void* src,
                                       int O, int K, int tid, int nt, bool f32) {
    for (int i = tid; i < O * K; i += nt) {
        int o = i / K, k = i % K;
        dst[k * O + o] = gload(src, i, f32);
    }
}
__device__ __forceinline__ void load_V(float* dst, const void* src,
                                       int n, int tid, int nt, bool f32) {
    for (int i = tid; i < n; i += nt) dst[i] = gload(src, i, f32);
}

__global__ __launch_bounds__(NTHREADS, 1)
void rnn_fused(const void* __restrict__ x,
               const void* __restrict__ dense_w,
               const void* __restrict__ dense_b,
               const void* __restrict__ vad_w_ih,
               const void* __restrict__ vad_w_hh,
               const void* __restrict__ vad_b_ih,
               const void* __restrict__ vad_b_hh,
               const void* __restrict__ vad_out_w,
               const void* __restrict__ vad_out_b,
               const void* __restrict__ noise_w_ih,
               const void* __restrict__ noise_w_hh,
               const void* __restrict__ noise_b_ih,
               const void* __restrict__ noise_b_hh,
               const void* __restrict__ den_w_ih,
               const void* __restrict__ den_w_hh,
               const void* __restrict__ den_b_ih,
               const void* __restrict__ den_b_hh,
               const void* __restrict__ out_w,
               const void* __restrict__ out_b,
               void* __restrict__ d_out) {
    // ---- LDS (~62.5 KiB, under the 64 KiB workgroup limit) ----
    __shared__ unsigned sVIHp[12 * 72];   // vad w_ih^T packed  (K=24)
    __shared__ unsigned sVHHp[12 * 72];   // vad w_hh^T packed  (K=24)
    __shared__ unsigned sNIHp[45 * 144];  // noise w_ih^T packed (K=90)
    __shared__ unsigned sNHHp[24 * 144];  // noise w_hh^T packed (K=48)
    __shared__ unsigned sOWp[48 * 22];    // out_w^T packed      (K=96)
    __shared__ float sDW[42 * 24];        // dense_w^T fp32
    __shared__ float sDB[24];
    __shared__ float sVBI[72], sVBH[72], sVOW[24], sVOB[1];
    __shared__ float sNBI[144], sNBH[144];
    __shared__ float sDBI[288], sDBH[288];
    __shared__ float sOB[22];
    __shared__ float sXT[FF];
    __shared__ float sTMP[HVAD];
    __shared__ float sHV[HVAD], sHN[HNOI], sHD[HDEN];
    __shared__ float sNIN[90];            // [tmp, vad, x]
    __shared__ float sDIN[114];           // [vad, relu(noise), x]
    __shared__ float sR[96], sZ[96], sXN[96], sHN2[96];
    __shared__ int sBad;

    const int tid = threadIdx.x;
    const int b = blockIdx.x;
    const int nt = NTHREADS;

    // ---- dtype detection: low 16 bits of dense_w words as bf16.
    // bf16 storage: genuine weights, |v| <= 0.21.  fp32 storage: random
    // mantissa bits -> huge/NaN values appear within 500 samples w.p. ~1.
    if (tid == 0) sBad = 0;
    __syncthreads();
    {
        const unsigned* w = (const unsigned*)dense_w;  // 500 words in-bounds either way
        for (int i = tid; i < 500; i += nt) {
            float av = fabsf(unpk_lo(w[i]));
            if (!(av <= 1e3f)) { atomicAdd(&sBad, 1); break; }
        }
    }
    __syncthreads();
    const bool F32 = (sBad > 0);

    const float* xbf = (const float*)x + (size_t)b * TT * FF;
    const __hip_bfloat16* xbh = (const __hip_bfloat16*)x + (size_t)b * TT * FF;
    float* odf = (float*)d_out;
    __hip_bfloat16* odh = (__hip_bfloat16*)d_out;
    float* ovf = odf + (size_t)BB * TT * 22;
    __hip_bfloat16* ovh = odh + (size_t)BB * TT * 22;

    // ---- load weights ----
    load_T (sDW,  dense_w,   24, 42, tid, nt, F32);
    load_V (sDB,  dense_b,   24, tid, nt, F32);
    load_Tp(sVIHp, vad_w_ih, 72, 12, tid, nt, F32);
    load_Tp(sVHHp, vad_w_hh, 72, 12, tid, nt, F32);
    load_V (sVBI, vad_b_ih,  72, tid, nt, F32);
    load_V (sVBH, vad_b_hh,  72, tid, nt, F32);
    load_V (sVOW, vad_out_w, 24, tid, nt, F32);
    if (tid == 0) sVOB[0] = gload(vad_out_b, 0, F32);
    load_Tp(sNIHp, noise_w_ih, 144, 45, tid, nt, F32);
    load_Tp(sNHHp, noise_w_hh, 144, 24, tid, nt, F32);
    load_V (sNBI, noise_b_ih, 144, tid, nt, F32);
    load_V (sNBH, noise_b_hh, 144, tid, nt, F32);
    load_V (sDBI, den_b_ih,  288, tid, nt, F32);
    load_V (sDBH, den_b_hh,  288, tid, nt, F32);
    load_Tp(sOWp, out_w,      22, 48, tid, nt, F32);
    load_V (sOB,  out_b,      22, tid, nt, F32);

    // ---- den weights: per-thread registers, bf16-pair packed ----
    unsigned wih[57];  // row tid of den_w_ih (114 elems)
    unsigned whh[48];  // row tid of den_w_hh (96 elems)
    if (tid < 288) {
        if (F32) {
            const float* p = (const float*)den_w_ih + (size_t)tid * 114;
            #pragma unroll
            for (int i = 0; i < 57; ++i) wih[i] = pack2(p[2 * i], p[2 * i + 1]);
            const float* q = (const float*)den_w_hh + (size_t)tid * 96;
            #pragma unroll
            for (int i = 0; i < 48; ++i) whh[i] = pack2(q[2 * i], q[2 * i + 1]);
        } else {
            const unsigned* p = (const unsigned*)den_w_ih + tid * 57;
            #pragma unroll
            for (int i = 0; i < 57; ++i) wih[i] = p[i];
            const unsigned* q = (const unsigned*)den_w_hh + tid * 48;
            #pragma unroll
            for (int i = 0; i < 48; ++i) whh[i] = q[i];
        }
    } else {
        #pragma unroll
        for (int i = 0; i < 57; ++i) wih[i] = 0u;
        #pragma unroll
        for (int i = 0; i < 48; ++i) whh[i] = 0u;
    }

    // ---- prologue ----
    for (int i = tid; i < 96; i += nt) {
        sR[i] = 0.f; sZ[i] = 0.f; sXN[i] = 0.f; sHN2[i] = 0.f; sHD[i] = 0.f;
    }
    for (int i = tid; i < 90;  i += nt) sNIN[i] = 0.f;
    for (int i = tid; i < 114; i += nt) sDIN[i] = 0.f;
    if (tid < HVAD) { sHV[tid] = 0.f; sTMP[tid] = 0.f; }
    if (tid < HNOI) sHN[tid] = 0.f;
    if (tid < FF) sXT[tid] = F32 ? xbf[tid] : bf2f(xbh[tid]);
    float xreg = 0.f;
    if (tid >= 128 && tid < 128 + FF) {
        int idx = FF + (tid - 128);
        xreg = F32 ? xbf[idx] : bf2f(xbh[idx]);
    }
    __syncthreads();

    for (int t = 0; t < TT; ++t) {
        // ---- stage B: dense(t)  ||  out head(t-1) ----
        if (tid < 24) {
            float a = sDB[tid];
            #pragma unroll
            for (int k = 0; k < 42; ++k) a += sDW[k * 24 + tid] * sXT[k];
            sTMP[tid] = tanhf(a);
        } else if (tid >= 192 && tid < 214) {
            if (t > 0) {
                int o = tid - 192;
                float a = sOB[o];
                #pragma unroll
                for (int kp = 0; kp < 48; ++kp) {
                    unsigned u = sOWp[kp * 22 + o];
                    a += unpk_lo(u) * fmaxf(sHD[2 * kp], 0.f)
                       + unpk_hi(u) * fmaxf(sHD[2 * kp + 1], 0.f);
                }
                size_t oi = ((size_t)b * TT + (t - 1)) * 22 + o;
                float v = sig(a);
                if (F32) odf[oi] = v; else odh[oi] = __float2bfloat16(v);
            }
        }
        __syncthreads();

        // ---- stage C: vad gates (72 threads) ----
        if (tid < 72) {
            float a = sVBI[tid], ah = sVBH[tid];
            #pragma unroll
            for (int kp = 0; kp < 12; ++kp) {
                unsigned u1 = sVIHp[kp * 72 + tid];
                a  += unpk_lo(u1) * sTMP[2 * kp] + unpk_hi(u1) * sTMP[2 * kp + 1];
                unsigned u2 = sVHHp[kp * 72 + tid];
                ah += unpk_lo(u2) * sHV[2 * kp] + unpk_hi(u2) * sHV[2 * kp + 1];
            }
            if (tid < 24)      sR[tid] = sig(a + ah);
            else if (tid < 48) sZ[tid - 24] = sig(a + ah);
            else { sXN[tid - 48] = a; sHN2[tid - 48] = ah; }
        }
        __syncthreads();

        // ---- stage D: vad update || build sNIN = [tmp, vad, x] ----
        if (tid < HVAD) {
            float r = sR[tid], z = sZ[tid];
            float n = tanhf(sXN[tid] + r * sHN2[tid]);
            float h = (1.f - z) * n + z * sHV[tid];
            sHV[tid] = h;
            sNIN[24 + tid] = h;
        } else if (tid >= 64 && tid < 88) {
            sNIN[tid - 64] = sTMP[tid - 64];
        } else if (tid >= 96 && tid < 96 + FF) {
            sNIN[48 + (tid - 96)] = sXT[tid - 96];
        }
        __syncthreads();

        // ---- stage E: noise gates (144 threads) ----
        if (tid < 144) {
            float a = sNBI[tid], ah = sNBH[tid];
            #pragma unroll
            for (int kp = 0; kp < 45; ++kp) {
                unsigned u = sNIHp[kp * 144 + tid];
                a += unpk_lo(u) * sNIN[2 * kp] + unpk_hi(u) * sNIN[2 * kp + 1];
            }
            #pragma unroll
            for (int kp = 0; kp < 24; ++kp) {
                unsigned u = sNHHp[kp * 144 + tid];
                ah += unpk_lo(u) * sHN[2 * kp] + unpk_hi(u) * sHN[2 * kp + 1];
            }
            if (tid < 48)      sR[tid] = sig(a + ah);
            else if (tid < 96) sZ[tid - 48] = sig(a + ah);
            else { sXN[tid - 96] = a; sHN2[tid - 96] = ah; }
        }
        __syncthreads();

        // ---- stage F: noise update || build sDIN = [vad, relu(noise), x] ----
        if (tid < HNOI) {
            float r = sR[tid], z = sZ[tid];
            float n = tanhf(sXN[tid] + r * sHN2[tid]);
            float h = (1.f - z) * n + z * sHN[tid];
            sHN[tid] = h;
            sDIN[24 + tid] = fmaxf(h, 0.f);
        } else if (tid >= 64 && tid < 88) {
            sDIN[tid - 64] = sHV[tid - 64];
        } else if (tid >= 96 && tid < 96 + FF) {
            sDIN[72 + (tid - 96)] = sXT[tid - 96];
        }
        __syncthreads();

        // ---- stage G: den gates (288 threads) ----
        if (tid < 288) {
            float a = sDBI[tid], ah = sDBH[tid];
            #pragma unroll
            for (int p = 0; p < 57; ++p) {
                unsigned u = wih[p];
                a += unpk_lo(u) * sDIN[2 * p] + unpk_hi(u) * sDIN[2 * p + 1];
            }
            #pragma unroll
            for (int p = 0; p < 48; ++p) {
                unsigned u = whh[p];
                ah += unpk_lo(u) * sHD[2 * p] + unpk_hi(u) * sHD[2 * p + 1];
            }
            if (tid < 96)       sR[tid] = sig(a + ah);
            else if (tid < 192) sZ[tid - 96] = sig(a + ah);
            else { sXN[tid - 192] = a; sHN2[tid - 192] = ah; }
        }
        __syncthreads();

        // ---- stage H: den update || x(t+1) staging || vad_out(t) ----
        if (tid < HDEN) {
            float r = sR[tid], z = sZ[tid];
            float n = tanhf(sXN[tid] + r * sHN2[tid]);
            sHD[tid] = (1.f - z) * n + z * sHD[tid];
        } else if (tid >= 128 && tid < 128 + FF) {
            if (t + 1 < TT) {
                sXT[tid - 128] = xreg;
                int t2 = (t + 2 < TT) ? (t + 2) : (TT - 1);
                int idx = t2 * FF + (tid - 128);
                xreg = F32 ? xbf[idx] : bf2f(xbh[idx]);
            }
        } else if (tid == 214) {
            float a = sVOB[0];
            #pragma unroll
            for (int k = 0; k < 24; ++k) a += sVOW[k] * sHV[k];
            size_t oi = (size_t)b * TT + t;
            float v = sig(a);
            if (F32) ovf[oi] = v; else ovh[oi] = __float2bfloat16(v);
        }
        __syncthreads();
    }

    // ---- epilogue: out head for t = T-1 ----
    if (tid >= 192 && tid < 214) {
        int o = tid - 192;
        float a = sOB[o];
        #pragma unroll
        for (int kp = 0; kp < 48; ++kp) {
            unsigned u = sOWp[kp * 22 + o];
            a += unpk_lo(u) * fmaxf(sHD[2 * kp], 0.f)
               + unpk_hi(u) * fmaxf(sHD[2 * kp + 1], 0.f);
        }
        size_t oi = ((size_t)b * TT + (TT - 1)) * 22 + o;
        float v = sig(a);
        if (F32) odf[oi] = v; else odh[oi] = __float2bfloat16(v);
    }
}

extern "C" void kernel_launch(void* const* d_in, const int* in_sizes, int n_in,
                              void* d_out, int out_size, void* d_ws, size_t ws_size,
                              hipStream_t stream) {
    hipLaunchKernelGGL(rnn_fused, dim3(BB), dim3(NTHREADS), 0, stream,
                       d_in[0], d_in[1], d_in[2],
                       d_in[3], d_in[4], d_in[5], d_in[6],
                       d_in[7], d_in[8],
                       d_in[9], d_in[10], d_in[11], d_in[12],
                       d_in[13], d_in[14], d_in[15], d_in[16],
                       d_in[17], d_in[18], d_out);
}